// Round 9
// baseline (71.453 us; speedup 1.0000x reference)
//
#include <hip/hip_runtime.h>

#define NN 50000
#define NE 800000
#define D  64
#define NB 196            // bins of 256 nodes: bin = dst >> 8
#define EBLK 2048         // edges per hist/scatter block
#define NEB 391           // ceil(NE / EBLK)
#define CAP3B 4608        // per-bin record cap for k3b LDS
#define CONVB 1563        // ceil(NN*D/8 / 256) conv blocks in prep

typedef unsigned int u32;
typedef unsigned short u16;
typedef unsigned long long u64;
typedef __attribute__((ext_vector_type(8))) short bf16x8;
typedef __attribute__((ext_vector_type(4))) float f32x4;

__device__ __forceinline__ int wave_incl_scan(int v, int lane) {
    #pragma unroll
    for (int off = 1; off < 64; off <<= 1) {
        int t = __shfl_up(v, off);
        if (lane >= off) v += t;
    }
    return v;
}

__device__ __forceinline__ u32 f2bf(float x) {       // RNE bf16 -> low 16 bits
    u32 u = __float_as_uint(x);
    return (u + 0x7fffu + ((u >> 16) & 1u)) >> 16;
}

__device__ __forceinline__ bf16x8 as_bf8(uint4 u) {
    union { uint4 a; bf16x8 b; } x; x.a = u; return x.b;
}

// ---------------------------------------------------------------------------
// prep: blocks [0,CONVB): feat -> fblo/fbhi (bf16 halves, features 0-31/32-63)
//       blocks [CONVB,+NEB): per-block bin histogram of dst.
// ---------------------------------------------------------------------------
__global__ __launch_bounds__(256) void prep_kernel(const float* __restrict__ feat,
                                                   uint4* __restrict__ fblo,
                                                   uint4* __restrict__ fbhi,
                                                   const int* __restrict__ dst,
                                                   u32* __restrict__ ghist)
{
    __shared__ u32 h[NB];
    int tid = threadIdx.x;
    if (blockIdx.x < CONVB) {
        int i = blockIdx.x * 256 + tid;
        if (i >= NN * D / 8) return;
        int n = i >> 3, off = i & 7;               // octet 'off' of node n
        const float4* f4 = (const float4*)feat;
        float4 a = f4[2 * i], b = f4[2 * i + 1];
        uint4 o;
        o.x = f2bf(a.x) | (f2bf(a.y) << 16);
        o.y = f2bf(a.z) | (f2bf(a.w) << 16);
        o.z = f2bf(b.x) | (f2bf(b.y) << 16);
        o.w = f2bf(b.z) | (f2bf(b.w) << 16);
        if (off < 4) fblo[n * 4 + off] = o;
        else         fbhi[n * 4 + off - 4] = o;
    } else {
        int blk = blockIdx.x - CONVB;
        if (tid < NB) h[tid] = 0;
        __syncthreads();
        int base = blk * EBLK;
        int n = min(EBLK, NE - base);
        for (int k = tid; k < n; k += 256)
            atomicAdd(&h[((u32)dst[base + k]) >> 8], 1u);
        __syncthreads();
        if (tid < NB) ghist[blk * NB + tid] = h[tid];
    }
}

// ---------------------------------------------------------------------------
// K2: per-bin exclusive scan over the 391 block counts -> bbase[blk][bin]
// ---------------------------------------------------------------------------
__global__ __launch_bounds__(256) void k2_scan(const u32* __restrict__ ghist,
                                               u32* __restrict__ bbase,
                                               u32* __restrict__ binTot)
{
    int gw = (blockIdx.x * 256 + threadIdx.x) >> 6;
    int lane = threadIdx.x & 63;
    if (gw >= NB) return;
    u32 run = 0;
    for (int c = 0; c < 7; ++c) {              // 7*64 = 448 >= 391
        int blk = c * 64 + lane;
        u32 v = (blk < NEB) ? ghist[blk * NB + gw] : 0;
        int incl = wave_incl_scan((int)v, lane);
        if (blk < NEB) bbase[blk * NB + gw] = (u32)incl - v + run;
        run += (u32)__shfl(incl, 63);
    }
    if (lane == 0) binTot[gw] = run;
}

// ---------------------------------------------------------------------------
// K3: bin scatter with LDS reorder (binStart scan done in-kernel).
// record: [dst:16][src:16][w_bits:32]
// ---------------------------------------------------------------------------
__global__ __launch_bounds__(256) void k3_scatter(const int* __restrict__ src,
                                                  const int* __restrict__ dst,
                                                  const float* __restrict__ ew,
                                                  const u32* __restrict__ bbase,
                                                  const u32* __restrict__ binTot,
                                                  u64* __restrict__ sorted)
{
    __shared__ u32 h[NB], eb[NB], ctr[NB], gb[NB], bS[NB];
    __shared__ u64 buf[EBLK];
    int tid = threadIdx.x;
    if (tid < NB) h[tid] = 0;
    __syncthreads();
    int base = blockIdx.x * EBLK;
    int n = min(EBLK, NE - base);
    for (int k = tid; k < n; k += 256)
        atomicAdd(&h[((u32)dst[base + k]) >> 8], 1u);
    __syncthreads();
    if (tid < 64) {
        u32 carry = 0;
        for (int c = 0; c < 4; ++c) {
            int idx = c * 64 + tid;
            u32 v = (idx < NB) ? h[idx] : 0;
            int incl = wave_incl_scan((int)v, tid);
            if (idx < NB) { u32 e = (u32)incl - v + carry; eb[idx] = e; ctr[idx] = e; }
            carry += (u32)__shfl(incl, 63);
        }
        u32 carry2 = 0;
        for (int c = 0; c < 4; ++c) {
            int idx = c * 64 + tid;
            u32 v = (idx < NB) ? binTot[idx] : 0;
            int incl = wave_incl_scan((int)v, tid);
            if (idx < NB) bS[idx] = (u32)incl - v + carry2;
            carry2 += (u32)__shfl(incl, 63);
        }
    }
    __syncthreads();
    if (tid < NB) gb[tid] = bbase[blockIdx.x * NB + tid] + bS[tid];
    __syncthreads();
    for (int k = tid; k < n; k += 256) {
        int e = base + k;
        u32 d = (u32)dst[e], s = (u32)src[e];
        u64 rec = ((u64)((d << 16) | s) << 32) | (u64)__float_as_uint(ew[e]);
        u32 p = atomicAdd(&ctr[d >> 8], 1u);
        buf[p] = rec;
    }
    __syncthreads();
    for (int k = tid; k < n; k += 256) {
        u64 rec = buf[k];
        u32 bin = (u32)(rec >> 56);
        sorted[gb[bin] + (u32)k - eb[bin]] = rec;
    }
}

// ---------------------------------------------------------------------------
// K3b: within-bin node sort (LDS). Emits u16 src stream (node-sorted),
// nodeStart CSR, and per-node edge-weight sums sW.
// ---------------------------------------------------------------------------
__global__ __launch_bounds__(256) void k3b_nodesort(const u64* __restrict__ sorted,
                                                    const u32* __restrict__ binTot,
                                                    u16* __restrict__ srcs16,
                                                    u32* __restrict__ nodeStart,
                                                    float* __restrict__ sW)
{
    __shared__ u32 hcnt[256], hbase[257], ctr[256], bS[257];
    __shared__ u64 buf[CAP3B];
    int tid = threadIdx.x;
    int bin = blockIdx.x;

    if (tid < 64) {                            // binStart scan (exclusive, +total)
        u32 carry = 0;
        for (int c = 0; c < 4; ++c) {
            int idx = c * 64 + tid;
            u32 v = (idx < NB) ? binTot[idx] : 0;
            int incl = wave_incl_scan((int)v, tid);
            if (idx <= NB) bS[idx] = (u32)incl - v + carry;
            carry += (u32)__shfl(incl, 63);
        }
    }
    if (tid < 256) hcnt[tid] = 0;
    __syncthreads();
    int beg = (int)bS[bin];
    int n = (int)bS[bin + 1] - beg;
    if (n > CAP3B) n = CAP3B;

    for (int k = tid; k < n; k += 256) {
        u64 rec = sorted[beg + k];
        atomicAdd(&hcnt[(int)(rec >> 48) & 255], 1u);
    }
    __syncthreads();
    if (tid < 64) {
        u32 carry = 0;
        for (int c = 0; c < 4; ++c) {
            int idx = c * 64 + tid;
            u32 v = hcnt[idx];
            int incl = wave_incl_scan((int)v, tid);
            u32 ex = (u32)incl - v + carry;
            hbase[idx] = ex; ctr[idx] = ex;
            carry += (u32)__shfl(incl, 63);
        }
        if (tid == 63) hbase[256] = carry;
    }
    __syncthreads();
    for (int k = tid; k < n; k += 256) {
        u64 rec = sorted[beg + k];
        u32 p = atomicAdd(&ctr[(int)(rec >> 48) & 255], 1u);
        buf[p] = rec;
    }
    __syncthreads();
    for (int k = tid; k < n; k += 256)
        srcs16[beg + k] = (u16)(buf[k] >> 32);
    nodeStart[(bin << 8) + tid] = (u32)beg + hbase[tid];
    if (bin == NB - 1 && tid == 0)
        nodeStart[NB << 8] = (u32)beg + hbase[256];
    {
        int node = (bin << 8) + tid;
        if (node < NN) {
            float s = 0.f;
            for (int j = (int)hbase[tid]; j < (int)hbase[tid + 1]; ++j)
                s += __uint_as_float((u32)buf[j]);
            sW[node] = s;
        }
    }
}

// ---------------------------------------------------------------------------
// K4: L2-resident half-gather. fb = one 3.2MB half (fits per-XCD L2).
// 8-lane group per node (8 nodes/wave); 4-deep unroll.
// ---------------------------------------------------------------------------
__global__ __launch_bounds__(256) void k4_gather(const uint2* __restrict__ fb,
                                                 const u16* __restrict__ srcs16,
                                                 const u32* __restrict__ nodeStart,
                                                 uint2* __restrict__ aggh)
{
    int node = blockIdx.x * 32 + (threadIdx.x >> 3);
    int li   = threadIdx.x & 7;
    if (node >= NN) return;

    int e   = (int)nodeStart[node];
    int end = (int)nodeStart[node + 1];

    float4 acc = make_float4(0.f, 0.f, 0.f, 0.f);
    for (; e + 3 < end; e += 4) {
        int s0 = srcs16[e],     s1 = srcs16[e + 1];
        int s2 = srcs16[e + 2], s3 = srcs16[e + 3];
        uint2 u0 = fb[(size_t)s0 * 8 + li];
        uint2 u1 = fb[(size_t)s1 * 8 + li];
        uint2 u2 = fb[(size_t)s2 * 8 + li];
        uint2 u3 = fb[(size_t)s3 * 8 + li];
        acc.x += __uint_as_float(u0.x << 16) + __uint_as_float(u1.x << 16)
               + __uint_as_float(u2.x << 16) + __uint_as_float(u3.x << 16);
        acc.y += __uint_as_float(u0.x & 0xffff0000u) + __uint_as_float(u1.x & 0xffff0000u)
               + __uint_as_float(u2.x & 0xffff0000u) + __uint_as_float(u3.x & 0xffff0000u);
        acc.z += __uint_as_float(u0.y << 16) + __uint_as_float(u1.y << 16)
               + __uint_as_float(u2.y << 16) + __uint_as_float(u3.y << 16);
        acc.w += __uint_as_float(u0.y & 0xffff0000u) + __uint_as_float(u1.y & 0xffff0000u)
               + __uint_as_float(u2.y & 0xffff0000u) + __uint_as_float(u3.y & 0xffff0000u);
    }
    for (; e < end; ++e) {
        int s0 = srcs16[e];
        uint2 u0 = fb[(size_t)s0 * 8 + li];
        acc.x += __uint_as_float(u0.x << 16);
        acc.y += __uint_as_float(u0.x & 0xffff0000u);
        acc.z += __uint_as_float(u0.y << 16);
        acc.w += __uint_as_float(u0.y & 0xffff0000u);
    }

    uint2 o;
    o.x = f2bf(acc.x) | (f2bf(acc.y) << 16);
    o.y = f2bf(acc.z) | (f2bf(acc.w) << 16);
    aggh[(size_t)node * 8 + li] = o;
}

// ---------------------------------------------------------------------------
// MFMA epilogue: out = [flo|fhi|alo|ahi] @ [W1;W2]_bf16 - sW ⊗ csum(W2)
// A-frag: row = lane&15, k-octet q = lane>>4 per 32-K block.
// D layout: col = lane&15, row = 4*(lane>>4)+reg.
// ---------------------------------------------------------------------------
__global__ __launch_bounds__(256) void gemm_mfma(
    const uint4* __restrict__ flo,     // [NN][4] uint4 = feat cols 0-31
    const uint4* __restrict__ fhi,     // cols 32-63
    const uint4* __restrict__ alo,     // agg cols 0-31
    const uint4* __restrict__ ahi,     // agg cols 32-63
    const float* __restrict__ sW,
    const float* __restrict__ W1,
    const float* __restrict__ W2,
    float* __restrict__ out)
{
    __shared__ unsigned short wT[64][136];  // Wcat^T bf16, padded
    __shared__ float csp[4][64];
    __shared__ float csum[64];
    const int tid = threadIdx.x;

    for (int i = tid; i < 8192; i += 256) {
        int k = i >> 6, c = i & 63;
        float v = (k < 64) ? W1[i] : W2[i - 4096];
        wT[c][k] = (unsigned short)f2bf(v);
    }
    {
        int c = tid & 63, kq = tid >> 6;
        float s = 0.f;
        for (int k = kq * 16; k < kq * 16 + 16; ++k) s += W2[k * 64 + c];
        csp[kq][c] = s;
    }
    __syncthreads();
    if (tid < 64) csum[tid] = csp[0][tid] + csp[1][tid] + csp[2][tid] + csp[3][tid];
    __syncthreads();

    int gw = blockIdx.x * 4 + (tid >> 6);
    if (gw >= NN / 16) return;
    const int l  = tid & 63;
    const int lr = l & 15;
    const int q  = l >> 4;

    bf16x8 b[4][4];
    #pragma unroll
    for (int nt = 0; nt < 4; ++nt)
        #pragma unroll
        for (int kk = 0; kk < 4; ++kk)
            b[nt][kk] = *(const bf16x8*)&wT[nt * 16 + lr][kk * 32 + q * 8];

    const int m0 = gw * 16;
    const size_t row = (size_t)(m0 + lr) * 4;
    bf16x8 a0 = as_bf8(flo[row + q]);
    bf16x8 a1 = as_bf8(fhi[row + q]);
    bf16x8 a2 = as_bf8(alo[row + q]);
    bf16x8 a3 = as_bf8(ahi[row + q]);

    f32x4 acc0 = {0.f, 0.f, 0.f, 0.f};
    f32x4 acc1 = acc0, acc2 = acc0, acc3 = acc0;

    acc0 = __builtin_amdgcn_mfma_f32_16x16x32_bf16(a0, b[0][0], acc0, 0, 0, 0);
    acc1 = __builtin_amdgcn_mfma_f32_16x16x32_bf16(a0, b[1][0], acc1, 0, 0, 0);
    acc2 = __builtin_amdgcn_mfma_f32_16x16x32_bf16(a0, b[2][0], acc2, 0, 0, 0);
    acc3 = __builtin_amdgcn_mfma_f32_16x16x32_bf16(a0, b[3][0], acc3, 0, 0, 0);

    acc0 = __builtin_amdgcn_mfma_f32_16x16x32_bf16(a1, b[0][1], acc0, 0, 0, 0);
    acc1 = __builtin_amdgcn_mfma_f32_16x16x32_bf16(a1, b[1][1], acc1, 0, 0, 0);
    acc2 = __builtin_amdgcn_mfma_f32_16x16x32_bf16(a1, b[2][1], acc2, 0, 0, 0);
    acc3 = __builtin_amdgcn_mfma_f32_16x16x32_bf16(a1, b[3][1], acc3, 0, 0, 0);

    acc0 = __builtin_amdgcn_mfma_f32_16x16x32_bf16(a2, b[0][2], acc0, 0, 0, 0);
    acc1 = __builtin_amdgcn_mfma_f32_16x16x32_bf16(a2, b[1][2], acc1, 0, 0, 0);
    acc2 = __builtin_amdgcn_mfma_f32_16x16x32_bf16(a2, b[2][2], acc2, 0, 0, 0);
    acc3 = __builtin_amdgcn_mfma_f32_16x16x32_bf16(a2, b[3][2], acc3, 0, 0, 0);

    acc0 = __builtin_amdgcn_mfma_f32_16x16x32_bf16(a3, b[0][3], acc0, 0, 0, 0);
    acc1 = __builtin_amdgcn_mfma_f32_16x16x32_bf16(a3, b[1][3], acc1, 0, 0, 0);
    acc2 = __builtin_amdgcn_mfma_f32_16x16x32_bf16(a3, b[2][3], acc2, 0, 0, 0);
    acc3 = __builtin_amdgcn_mfma_f32_16x16x32_bf16(a3, b[3][3], acc3, 0, 0, 0);

    float4 sw4 = *(const float4*)&sW[m0 + q * 4];
    const float* swp = (const float*)&sw4;

    #pragma unroll
    for (int r = 0; r < 4; ++r) {
        size_t rowoff = (size_t)(m0 + q * 4 + r) * D;
        float s = swp[r];
        out[rowoff +  0 + lr] = acc0[r] - s * csum[ 0 + lr];
        out[rowoff + 16 + lr] = acc1[r] - s * csum[16 + lr];
        out[rowoff + 32 + lr] = acc2[r] - s * csum[32 + lr];
        out[rowoff + 48 + lr] = acc3[r] - s * csum[48 + lr];
    }
}

// ---------------------------------------------------------------------------
extern "C" void kernel_launch(void* const* d_in, const int* in_sizes, int n_in,
                              void* d_out, int out_size, void* d_ws, size_t ws_size,
                              hipStream_t stream)
{
    const float* feat = (const float*)d_in[0];
    const float* ew   = (const float*)d_in[1];
    const float* W1   = (const float*)d_in[2];
    const float* W2   = (const float*)d_in[3];
    const int*   src  = (const int*)  d_in[4];
    const int*   dst  = (const int*)  d_in[5];
    float* out = (float*)d_out;

    // workspace (~22 MB of 256 MB; every buffer fully written before read)
    char* p = (char*)d_ws;
    size_t o = 0;
    auto take = [&](size_t bytes) { char* q = p + o; o = (o + bytes + 255) & ~(size_t)255; return q; };
    u64* sorted    = (u64*)take((size_t)NE * 8);             // 6.4 MB
    u32* ghist     = (u32*)take((size_t)NEB * NB * 4);
    u32* bbase     = (u32*)take((size_t)NEB * NB * 4);
    u32* binTot    = (u32*)take((size_t)NB * 4);
    u32* nodeStart = (u32*)take((size_t)(NB * 256 + 1) * 4);
    u16* srcs16    = (u16*)take((size_t)NE * 2);             // 1.6 MB
    uint4* fblo    = (uint4*)take((size_t)NN * 64);          // 3.2 MB (cols 0-31)
    uint4* fbhi    = (uint4*)take((size_t)NN * 64);          // 3.2 MB (cols 32-63)
    uint4* agglo   = (uint4*)take((size_t)NN * 64);          // 3.2 MB
    uint4* agghi   = (uint4*)take((size_t)NN * 64);          // 3.2 MB
    float* sW      = (float*)take((size_t)NN * 4);

    prep_kernel <<<CONVB + NEB, 256, 0, stream>>>(feat, fblo, fbhi, dst, ghist);
    k2_scan     <<<(NB * 64 + 255) / 256, 256, 0, stream>>>(ghist, bbase, binTot);
    k3_scatter  <<<NEB, 256, 0, stream>>>(src, dst, ew, bbase, binTot, sorted);
    k3b_nodesort<<<NB, 256, 0, stream>>>(sorted, binTot, srcs16, nodeStart, sW);
    k4_gather   <<<(NN + 31) / 32, 256, 0, stream>>>((const uint2*)fblo, srcs16,
                                                     nodeStart, (uint2*)agglo);
    k4_gather   <<<(NN + 31) / 32, 256, 0, stream>>>((const uint2*)fbhi, srcs16,
                                                     nodeStart, (uint2*)agghi);
    gemm_mfma   <<<(NN / 16 + 3) / 4, 256, 0, stream>>>(fblo, fbhi, agglo, agghi,
                                                        sW, W1, W2, out);
}